// Round 2
// baseline (18273.543 us; speedup 1.0000x reference)
//
#include <hip/hip_runtime.h>
#include <hip/hip_bf16.h>

typedef unsigned short u16;
typedef unsigned int   u32;

#define CH   192
#define NH   8
#define HD   24
#define HWD  256
#define LDW  200   // LDS row stride (bf16 elems) for 192-wide rows (400B, 16B-aligned)
#define LDK  32    // LDS row stride for 24-wide rows (kernel2 k/v)
#define QSTR 28    // LDS row stride (f32) for kernel1 q/k/v
#define SCALE 0.20412414523193154f

__device__ __forceinline__ float bf2f(u16 u){ u32 v = ((u32)u) << 16; return __builtin_bit_cast(float, v); }
__device__ __forceinline__ u16 f2bf(float f){
  u32 u = __builtin_bit_cast(u32, f);
  u = (u + 0x7fffu + ((u >> 16) & 1u)) >> 16;
  return (u16)u;
}
__device__ __forceinline__ float lo2f(u32 p){ return __builtin_bit_cast(float, p << 16); }
__device__ __forceinline__ float hi2f(u32 p){ return __builtin_bit_cast(float, p & 0xffff0000u); }

// unpack 8 bf16 (LDS) -> 8 f32
__device__ __forceinline__ void up8(uint4 q, float* f){
  f[0]=lo2f(q.x); f[1]=hi2f(q.x); f[2]=lo2f(q.y); f[3]=hi2f(q.y);
  f[4]=lo2f(q.z); f[5]=hi2f(q.z); f[6]=lo2f(q.w); f[7]=hi2f(q.w);
}
// load 8 f32 from global (two float4)
__device__ __forceinline__ void ldw8(const float* __restrict__ p, float* f){
  float4 a = *reinterpret_cast<const float4*>(p);
  float4 b = *reinterpret_cast<const float4*>(p + 4);
  f[0]=a.x; f[1]=a.y; f[2]=a.z; f[3]=a.w;
  f[4]=b.x; f[5]=b.y; f[6]=b.z; f[7]=b.w;
}

// LayerNorm over 192 channels, rows = 64 tokens, 8 lanes per row. src/dst LDS bf16 [64][LDW].
__device__ __forceinline__ void layernorm_ln(const u16* __restrict__ src, u16* __restrict__ dst,
                                             const float* __restrict__ g, const float* __restrict__ b,
                                             int tid)
{
  int r = tid >> 3, sub = tid & 7;
  const u16* row = src + r*LDW + sub*24;
  float v[24];
  float s = 0.f, s2 = 0.f;
  #pragma unroll
  for (int e = 0; e < 24; ++e){ v[e] = bf2f(row[e]); s += v[e]; s2 += v[e]*v[e]; }
  s  += __shfl_xor(s, 1, 64);  s  += __shfl_xor(s, 2, 64);  s  += __shfl_xor(s, 4, 64);
  s2 += __shfl_xor(s2, 1, 64); s2 += __shfl_xor(s2, 2, 64); s2 += __shfl_xor(s2, 4, 64);
  float m   = s * (1.f/192.f);
  float var = s2 * (1.f/192.f) - m*m;
  float rs  = rsqrtf(var + 1e-5f);
  u16* drow = dst + r*LDW + sub*24;
  const float* gp = g + sub*24;
  const float* bp = b + sub*24;
  #pragma unroll
  for (int e = 0; e < 24; ++e)
    drow[e] = f2bf((v[e] - m) * rs * gp[e] + bp[e]);
}

// GEMM tile: 8 tokens x 3 cols per thread; A rows in LDS bf16 [64][LDW]; 3 weight rows f32 global, K=192.
__device__ __forceinline__ void gemm83(const u16* __restrict__ a_lds,
                                       const float* __restrict__ w0,
                                       const float* __restrict__ w1,
                                       const float* __restrict__ w2,
                                       int tg, float (*acc)[3])
{
  for (int k0 = 0; k0 < 192; k0 += 8) {
    float w[3][8];
    ldw8(w0 + k0, w[0]);
    ldw8(w1 + k0, w[1]);
    ldw8(w2 + k0, w[2]);
    #pragma unroll
    for (int tt = 0; tt < 8; ++tt) {
      float a[8];
      up8(*reinterpret_cast<const uint4*>(a_lds + (tg*8+tt)*LDW + k0), a);
      #pragma unroll
      for (int e = 0; e < 8; ++e) {
        acc[tt][0] += a[e]*w[0][e];
        acc[tt][1] += a[e]*w[1][e];
        acc[tt][2] += a[e]*w[2][e];
      }
    }
  }
}

// ---------------- Kernel 1: window MSA + MLP; writes out = x + alpha * x_win ----------------
__global__ __launch_bounds__(512) void k_msa(
    const float* __restrict__ x, const float* __restrict__ g1, const float* __restrict__ b1,
    const float* __restrict__ qkv_w, const float* __restrict__ rpe, const float* __restrict__ wproj,
    const float* __restrict__ g2, const float* __restrict__ b2,
    const float* __restrict__ mlp1, const float* __restrict__ mlp2,
    const float* __restrict__ alpha_p, float* __restrict__ out)
{
  __shared__ __align__(16) u16 sX[64*LDW];   // orig window; later xn2 (LN2 out)
  __shared__ __align__(16) u16 sN[64*LDW];   // xn1; later xw2 (post-MSA residual)
  __shared__ __align__(16) u16 sM[64*LDW];   // msa concat; later gelu buf; later x_win stage
  __shared__ __align__(16) float sQ[64*QSTR];
  __shared__ __align__(16) float sK[64*QSTR];
  __shared__ __align__(16) float sV[64*QSTR];

  const int tid = threadIdx.x;
  const int win = blockIdx.x;
  const int b  = win >> 10;
  const int wy = (win >> 5) & 31;
  const int wx = win & 31;
  const int hrow = wy*8, wcol = wx*8;
  const float* xb = x + (size_t)b*CH*HWD*HWD;
  float* outb = out + (size_t)b*CH*HWD*HWD;

  // P0: load window (b,c,h,w) f32 -> sX[t][c] bf16
  for (int j = tid; j < 1536; j += 512) {
    int c = j >> 3, ty = j & 7;
    const float* src = xb + ((size_t)c*HWD + hrow + ty)*HWD + wcol;
    float4 a = *reinterpret_cast<const float4*>(src);
    float4 q = *reinterpret_cast<const float4*>(src + 4);
    u16* dst = &sX[(ty*8)*LDW + c];
    dst[0*LDW]=f2bf(a.x); dst[1*LDW]=f2bf(a.y); dst[2*LDW]=f2bf(a.z); dst[3*LDW]=f2bf(a.w);
    dst[4*LDW]=f2bf(q.x); dst[5*LDW]=f2bf(q.y); dst[6*LDW]=f2bf(q.z); dst[7*LDW]=f2bf(q.w);
  }
  __syncthreads();

  // P1: LN1
  layernorm_ln(sX, sN, g1, b1, tid);
  __syncthreads();

  const int t8 = tid >> 3, s8 = tid & 7;

  // P2: per-head qkv + attention (RPE bias)
  for (int h = 0; h < NH; ++h) {
    { // qkv: each thread computes 3 q + 3 k + 3 v values for token t8
      const u16* arow = &sN[t8*LDW];
      float acc[9];
      #pragma unroll
      for (int o = 0; o < 9; ++o) acc[o] = 0.f;
      const float* wp[9];
      #pragma unroll
      for (int o = 0; o < 3; ++o) {
        const float* base = qkv_w + (size_t)(h*24 + s8*3 + o)*192;
        wp[o]   = base;
        wp[3+o] = base + 192*192;
        wp[6+o] = base + 2*192*192;
      }
      for (int k0 = 0; k0 < 192; k0 += 8) {
        float a[8]; up8(*reinterpret_cast<const uint4*>(arow + k0), a);
        #pragma unroll
        for (int o = 0; o < 9; ++o) {
          float w[8]; ldw8(wp[o] + k0, w);
          #pragma unroll
          for (int e = 0; e < 8; ++e) acc[o] += a[e]*w[e];
        }
      }
      float* qd = &sQ[t8*QSTR + s8*3];
      float* kd = &sK[t8*QSTR + s8*3];
      float* vd = &sV[t8*QSTR + s8*3];
      #pragma unroll
      for (int o = 0; o < 3; ++o){ qd[o] = acc[o]; kd[o] = acc[3+o]; vd[o] = acc[6+o]; }
    }
    __syncthreads();
    { // attention: row r=t8, lane s8 owns cols s8*8..s8*8+7
      float q24[24];
      #pragma unroll
      for (int e = 0; e < 24; ++e) q24[e] = sQ[t8*QSTR + e];
      const int ry = t8 >> 3, rx = t8 & 7;
      float p[8];
      #pragma unroll
      for (int j = 0; j < 8; ++j) {
        int c = s8*8 + j;
        const float* kr = &sK[c*QSTR];
        float s = 0.f;
        #pragma unroll
        for (int e = 0; e < 24; ++e) s += q24[e]*kr[e];
        int cy = c >> 3, cx = c & 7;
        int idx = (ry - cy + 7)*15 + (rx - cx + 7);
        p[j] = s*SCALE + rpe[idx*NH + h];
      }
      float mx = p[0];
      #pragma unroll
      for (int j = 1; j < 8; ++j) mx = fmaxf(mx, p[j]);
      mx = fmaxf(mx, __shfl_xor(mx, 1, 64));
      mx = fmaxf(mx, __shfl_xor(mx, 2, 64));
      mx = fmaxf(mx, __shfl_xor(mx, 4, 64));
      float sum = 0.f;
      #pragma unroll
      for (int j = 0; j < 8; ++j){ p[j] = __expf(p[j] - mx); sum += p[j]; }
      sum += __shfl_xor(sum, 1, 64); sum += __shfl_xor(sum, 2, 64); sum += __shfl_xor(sum, 4, 64);
      float inv = 1.f / sum;
      float o24[24];
      #pragma unroll
      for (int e = 0; e < 24; ++e) o24[e] = 0.f;
      #pragma unroll
      for (int j = 0; j < 8; ++j) {
        const float* vr = &sV[(s8*8 + j)*QSTR];
        #pragma unroll
        for (int e = 0; e < 24; ++e) o24[e] += p[j]*vr[e];
      }
      #pragma unroll
      for (int e = 0; e < 24; ++e) {
        o24[e] += __shfl_xor(o24[e], 1, 64);
        o24[e] += __shfl_xor(o24[e], 2, 64);
        o24[e] += __shfl_xor(o24[e], 4, 64);
      }
      u16* mrow = &sM[t8*LDW + h*24 + s8*3];
      #pragma unroll
      for (int o = 0; o < 3; ++o) mrow[o] = f2bf(o24[s8*3 + o]*inv);
    }
    __syncthreads();
  }

  // P3: wproj + residual -> sN (= xw2)
  const int tg = tid >> 6, cg = tid & 63;
  {
    float acc[8][3];
    #pragma unroll
    for (int tt = 0; tt < 8; ++tt){ acc[tt][0]=0.f; acc[tt][1]=0.f; acc[tt][2]=0.f; }
    gemm83(sM, wproj + (size_t)(cg*3+0)*192,
               wproj + (size_t)(cg*3+1)*192,
               wproj + (size_t)(cg*3+2)*192, tg, acc);
    #pragma unroll
    for (int tt = 0; tt < 8; ++tt)
      #pragma unroll
      for (int j = 0; j < 3; ++j) {
        int t = tg*8+tt, c = cg*3+j;
        sN[t*LDW + c] = f2bf(acc[tt][j] + bf2f(sX[t*LDW + c]));
      }
  }
  __syncthreads();

  // P4: LN2: sN -> sX (= xn2)
  layernorm_ln(sN, sX, g2, b2, tid);
  __syncthreads();

  // P5: MLP (two 192-wide halves of the 384 hidden dim)
  float facc[8][3];
  #pragma unroll
  for (int tt = 0; tt < 8; ++tt){ facc[tt][0]=0.f; facc[tt][1]=0.f; facc[tt][2]=0.f; }
  for (int half = 0; half < 2; ++half) {
    { // g = gelu(xn2 @ mlp1_half^T) -> sM
      float acc[8][3];
      #pragma unroll
      for (int tt = 0; tt < 8; ++tt){ acc[tt][0]=0.f; acc[tt][1]=0.f; acc[tt][2]=0.f; }
      gemm83(sX, mlp1 + (size_t)(half*192 + cg*3+0)*192,
                 mlp1 + (size_t)(half*192 + cg*3+1)*192,
                 mlp1 + (size_t)(half*192 + cg*3+2)*192, tg, acc);
      #pragma unroll
      for (int tt = 0; tt < 8; ++tt)
        #pragma unroll
        for (int j = 0; j < 3; ++j) {
          float vv = acc[tt][j];
          float gl = 0.5f*vv*(1.f + erff(vv*0.70710678118654752f));
          sM[(tg*8+tt)*LDW + cg*3+j] = f2bf(gl);
        }
    }
    __syncthreads();
    { // facc += g @ mlp2_half^T
      gemm83(sM, mlp2 + (size_t)(cg*3+0)*384 + half*192,
                 mlp2 + (size_t)(cg*3+1)*384 + half*192,
                 mlp2 + (size_t)(cg*3+2)*384 + half*192, tg, facc);
    }
    __syncthreads();
  }

  // P6: stage x_win = xw2 + mlp_out into sM
  #pragma unroll
  for (int tt = 0; tt < 8; ++tt)
    #pragma unroll
    for (int j = 0; j < 3; ++j) {
      int t = tg*8+tt, c = cg*3+j;
      sM[t*LDW + c] = f2bf(bf2f(sN[t*LDW + c]) + facc[tt][j]);
    }
  __syncthreads();

  // P7: out = x + alpha * x_win   (coalesced float4 writes)
  float alpha = alpha_p[0];
  for (int j = tid; j < 1536; j += 512) {
    int c = j >> 3, ty = j & 7;
    size_t goff = ((size_t)c*HWD + hrow + ty)*HWD + wcol;
    const float* src = xb + goff;
    float4 a = *reinterpret_cast<const float4*>(src);
    float4 q = *reinterpret_cast<const float4*>(src + 4);
    float w[8];
    #pragma unroll
    for (int e = 0; e < 8; ++e) w[e] = bf2f(sM[(ty*8 + e)*LDW + c]);
    float4 o1 = make_float4(a.x + alpha*w[0], a.y + alpha*w[1], a.z + alpha*w[2], a.w + alpha*w[3]);
    float4 o2 = make_float4(q.x + alpha*w[4], q.y + alpha*w[5], q.z + alpha*w[6], q.w + alpha*w[7]);
    *reinterpret_cast<float4*>(outb + goff)     = o1;
    *reinterpret_cast<float4*>(outb + goff + 4) = o2;
  }
}

// ---------------- Kernel 2: overlapping cross-attention; out += (1-alpha) * x_oca ----------------
__device__ __forceinline__ int refl(int v){ v = v < 0 ? -v : v; return v < HWD ? v : 2*(HWD-1) - v; }

__global__ __launch_bounds__(512) void k_oca(
    const float* __restrict__ x, const float* __restrict__ og_p, const float* __restrict__ ob_p,
    const float* __restrict__ q_w, const float* __restrict__ kv_w, const float* __restrict__ oproj,
    const float* __restrict__ alpha_p, float* __restrict__ out)
{
  __shared__ __align__(16) u16 sW[64*LDW];    // xwin (residual + LN input)
  __shared__ __align__(16) u16 sN[64*LDW];    // LN out; later attention-out
  __shared__ __align__(16) u16 sQa[64*LDW];   // q full; later x_oca staging
  __shared__ __align__(16) u16 sU[144*LDW];   // unfolded 12x12 window
  __shared__ __align__(16) u16 sKb[144*LDK];
  __shared__ __align__(16) u16 sVb[144*LDK];

  const int tid = threadIdx.x;
  const int win = blockIdx.x;
  const int b  = win >> 10;
  const int wy = (win >> 5) & 31;
  const int wx = win & 31;
  const int hrow = wy*8, wcol = wx*8;
  const float* xb = x + (size_t)b*CH*HWD*HWD;
  float* outb = out + (size_t)b*CH*HWD*HWD;

  // P0a: load xwin
  for (int j = tid; j < 1536; j += 512) {
    int c = j >> 3, ty = j & 7;
    const float* src = xb + ((size_t)c*HWD + hrow + ty)*HWD + wcol;
    float4 a = *reinterpret_cast<const float4*>(src);
    float4 q = *reinterpret_cast<const float4*>(src + 4);
    u16* dst = &sW[(ty*8)*LDW + c];
    dst[0*LDW]=f2bf(a.x); dst[1*LDW]=f2bf(a.y); dst[2*LDW]=f2bf(a.z); dst[3*LDW]=f2bf(a.w);
    dst[4*LDW]=f2bf(q.x); dst[5*LDW]=f2bf(q.y); dst[6*LDW]=f2bf(q.z); dst[7*LDW]=f2bf(q.w);
  }
  // P0b: load unfolded 12x12 (reflect-padded) window
  for (int i = tid; i < 144*192; i += 512) {
    int c = i / 144, t = i - c*144;
    int ti = t / 12, tj = t - ti*12;
    int hs = refl(hrow + ti - 2);
    int ws = refl(wcol + tj - 2);
    sU[t*LDW + c] = f2bf(xb[((size_t)c*HWD + hs)*HWD + ws]);
  }
  __syncthreads();

  // P1: LN(og, ob)
  layernorm_ln(sW, sN, og_p, ob_p, tid);
  __syncthreads();

  // P2: q = xn @ q_w^T -> sQa
  const int tg = tid >> 6, cg = tid & 63;
  {
    float acc[8][3];
    #pragma unroll
    for (int tt = 0; tt < 8; ++tt){ acc[tt][0]=0.f; acc[tt][1]=0.f; acc[tt][2]=0.f; }
    gemm83(sN, q_w + (size_t)(cg*3+0)*192,
               q_w + (size_t)(cg*3+1)*192,
               q_w + (size_t)(cg*3+2)*192, tg, acc);
    #pragma unroll
    for (int tt = 0; tt < 8; ++tt)
      #pragma unroll
      for (int j = 0; j < 3; ++j)
        sQa[(tg*8+tt)*LDW + cg*3+j] = f2bf(acc[tt][j]);
  }
  __syncthreads();

  const int t8 = tid >> 3, s8 = tid & 7;
  for (int h = 0; h < NH; ++h) {
    { // k,v for this head: 144 tokens x 24 dims
      for (int i = tid; i < 144*24; i += 512) {
        int tok = i / 24, d = i - tok*24;
        const float* kw = kv_w + (size_t)(h*24 + d)*192;
        const float* vw = kv_w + (size_t)(192 + h*24 + d)*192;
        const u16* arow = &sU[tok*LDW];
        float ka[4] = {0.f,0.f,0.f,0.f}, va[4] = {0.f,0.f,0.f,0.f};
        for (int k0 = 0; k0 < 192; k0 += 8) {
          float a[8]; up8(*reinterpret_cast<const uint4*>(arow + k0), a);
          float kk[8]; ldw8(kw + k0, kk);
          float vv[8]; ldw8(vw + k0, vv);
          #pragma unroll
          for (int e = 0; e < 8; ++e){ ka[e&3] += a[e]*kk[e]; va[e&3] += a[e]*vv[e]; }
        }
        sKb[tok*LDK + d] = f2bf(ka[0]+ka[1]+ka[2]+ka[3]);
        sVb[tok*LDK + d] = f2bf(va[0]+va[1]+va[2]+va[3]);
      }
    }
    __syncthreads();
    { // attention: row r=t8, lane s8 owns cols s8*18..s8*18+17 (144 keys)
      float q24[24];
      #pragma unroll
      for (int e = 0; e < 24; ++e) q24[e] = bf2f(sQa[t8*LDW + h*24 + e]);
      float p[18];
      #pragma unroll
      for (int j = 0; j < 18; ++j) {
        int c = s8*18 + j;
        const u16* kr = &sKb[c*LDK];
        float s = 0.f;
        #pragma unroll
        for (int e = 0; e < 24; ++e) s += q24[e]*bf2f(kr[e]);
        p[j] = s*SCALE;
      }
      float mx = p[0];
      #pragma unroll
      for (int j = 1; j < 18; ++j) mx = fmaxf(mx, p[j]);
      mx = fmaxf(mx, __shfl_xor(mx, 1, 64));
      mx = fmaxf(mx, __shfl_xor(mx, 2, 64));
      mx = fmaxf(mx, __shfl_xor(mx, 4, 64));
      float sum = 0.f;
      #pragma unroll
      for (int j = 0; j < 18; ++j){ p[j] = __expf(p[j] - mx); sum += p[j]; }
      sum += __shfl_xor(sum, 1, 64); sum += __shfl_xor(sum, 2, 64); sum += __shfl_xor(sum, 4, 64);
      float inv = 1.f / sum;
      float o24[24];
      #pragma unroll
      for (int e = 0; e < 24; ++e) o24[e] = 0.f;
      #pragma unroll
      for (int j = 0; j < 18; ++j) {
        const u16* vr = &sVb[(s8*18 + j)*LDK];
        #pragma unroll
        for (int e = 0; e < 24; ++e) o24[e] += p[j]*bf2f(vr[e]);
      }
      #pragma unroll
      for (int e = 0; e < 24; ++e) {
        o24[e] += __shfl_xor(o24[e], 1, 64);
        o24[e] += __shfl_xor(o24[e], 2, 64);
        o24[e] += __shfl_xor(o24[e], 4, 64);
      }
      u16* orow = &sN[t8*LDW + h*24 + s8*3];
      #pragma unroll
      for (int o = 0; o < 3; ++o) orow[o] = f2bf(o24[s8*3 + o]*inv);
    }
    __syncthreads();
  }

  // P4: oproj + residual -> sQa (= x_oca)
  {
    float acc[8][3];
    #pragma unroll
    for (int tt = 0; tt < 8; ++tt){ acc[tt][0]=0.f; acc[tt][1]=0.f; acc[tt][2]=0.f; }
    gemm83(sN, oproj + (size_t)(cg*3+0)*192,
               oproj + (size_t)(cg*3+1)*192,
               oproj + (size_t)(cg*3+2)*192, tg, acc);
    #pragma unroll
    for (int tt = 0; tt < 8; ++tt)
      #pragma unroll
      for (int j = 0; j < 3; ++j) {
        int t = tg*8+tt, c = cg*3+j;
        sQa[t*LDW + c] = f2bf(acc[tt][j] + bf2f(sW[t*LDW + c]));
      }
  }
  __syncthreads();

  // P5: out += (1 - alpha) * x_oca  (RMW, coalesced float4)
  float beta = 1.f - alpha_p[0];
  for (int j = tid; j < 1536; j += 512) {
    int c = j >> 3, ty = j & 7;
    size_t goff = ((size_t)c*HWD + hrow + ty)*HWD + wcol;
    float* dst = outb + goff;
    float4 a = *reinterpret_cast<const float4*>(dst);
    float4 q = *reinterpret_cast<const float4*>(dst + 4);
    float w[8];
    #pragma unroll
    for (int e = 0; e < 8; ++e) w[e] = bf2f(sQa[(ty*8 + e)*LDW + c]);
    float4 o1 = make_float4(a.x + beta*w[0], a.y + beta*w[1], a.z + beta*w[2], a.w + beta*w[3]);
    float4 o2 = make_float4(q.x + beta*w[4], q.y + beta*w[5], q.z + beta*w[6], q.w + beta*w[7]);
    *reinterpret_cast<float4*>(dst)     = o1;
    *reinterpret_cast<float4*>(dst + 4) = o2;
  }
}

extern "C" void kernel_launch(void* const* d_in, const int* in_sizes, int n_in,
                              void* d_out, int out_size, void* d_ws, size_t ws_size,
                              hipStream_t stream) {
  const float* x     = (const float*)d_in[0];
  const float* g1    = (const float*)d_in[1];
  const float* b1    = (const float*)d_in[2];
  const float* qkvw  = (const float*)d_in[3];
  const float* rpe   = (const float*)d_in[4];
  const float* wproj = (const float*)d_in[5];
  const float* g2    = (const float*)d_in[6];
  const float* b2    = (const float*)d_in[7];
  const float* mlp1  = (const float*)d_in[8];
  const float* mlp2  = (const float*)d_in[9];
  const float* alpha = (const float*)d_in[10];
  const float* og    = (const float*)d_in[11];
  const float* ob    = (const float*)d_in[12];
  const float* q_w   = (const float*)d_in[13];
  const float* kv_w  = (const float*)d_in[14];
  const float* oproj = (const float*)d_in[15];
  float* out = (float*)d_out;

  k_msa<<<2048, 512, 0, stream>>>(x, g1, b1, qkvw, rpe, wproj, g2, b2, mlp1, mlp2, alpha, out);
  k_oca<<<2048, 512, 0, stream>>>(x, og, ob, q_w, kv_w, oproj, alpha, out);
}

// Round 3
// 1750.449 us; speedup vs baseline: 10.4393x; 10.4393x over previous
//
#include <hip/hip_runtime.h>
#include <hip/hip_bf16.h>

typedef unsigned short u16;
typedef unsigned int   u32;
typedef __attribute__((ext_vector_type(8))) short bf16x8;
typedef __attribute__((ext_vector_type(4))) float f32x4;

#define CH   192
#define NH   8
#define HWD  256
#define LDW  200   // bf16 row stride for 192-wide LDS tiles (400B)
#define LDK  40    // bf16 row stride for 24-wide k/v rows (80B; 18-row lane stride -> 2-way, free)
#define QSTR 28
#define SCALE 0.20412414523193154f

__device__ __forceinline__ float bf2f(u16 u){ u32 v = ((u32)u) << 16; return __builtin_bit_cast(float, v); }
__device__ __forceinline__ u16 f2bf(float f){
  u32 u = __builtin_bit_cast(u32, f);
  u = (u + 0x7fffu + ((u >> 16) & 1u)) >> 16;
  return (u16)u;
}
__device__ __forceinline__ float lo2f(u32 p){ return __builtin_bit_cast(float, p << 16); }
__device__ __forceinline__ float hi2f(u32 p){ return __builtin_bit_cast(float, p & 0xffff0000u); }
__device__ __forceinline__ void up8(uint4 q, float* f){
  f[0]=lo2f(q.x); f[1]=hi2f(q.x); f[2]=lo2f(q.y); f[3]=hi2f(q.y);
  f[4]=lo2f(q.z); f[5]=hi2f(q.z); f[6]=lo2f(q.w); f[7]=hi2f(q.w);
}
__device__ __forceinline__ void ldw8(const float* __restrict__ p, float* f){
  float4 a = *reinterpret_cast<const float4*>(p);
  float4 b = *reinterpret_cast<const float4*>(p + 4);
  f[0]=a.x; f[1]=a.y; f[2]=a.z; f[3]=a.w;
  f[4]=b.x; f[5]=b.y; f[6]=b.z; f[7]=b.w;
}
__device__ __forceinline__ int refl(int v){ v = v < 0 ? -v : v; return v < HWD ? v : 2*(HWD-1) - v; }
__device__ __forceinline__ f32x4 mfma16(bf16x8 a, bf16x8 b, f32x4 c){
  return __builtin_amdgcn_mfma_f32_16x16x32_bf16(a, b, c, 0, 0, 0);
}
// A fragment from LDS bf16 buffer (u16 units): row-major, 16B aligned.
__device__ __forceinline__ bf16x8 afrag(const u16* pool, int base, int stride, int row, int kt, int l){
  return *reinterpret_cast<const bf16x8*>(pool + base + row*stride + kt*32 + ((l>>4)<<3));
}
// B fragment from swizzled weight buffer: tile-major, lane-contiguous.
__device__ __forceinline__ bf16x8 bfrag(const u16* __restrict__ w, int tile, int l){
  return *reinterpret_cast<const bf16x8*>(w + tile*512 + l*8);
}
// LN stats (mean, rsqrt) per 64 rows of a stride-200 bf16 LDS buffer.
__device__ __forceinline__ void ln_stats(const u16* buf, float* st, int tid){
  int r = tid >> 3, sub = tid & 7;
  const uint4* rp = reinterpret_cast<const uint4*>(buf + r*LDW + sub*24);
  float v[24]; up8(rp[0], v); up8(rp[1], v+8); up8(rp[2], v+16);
  float s = 0.f, s2 = 0.f;
  #pragma unroll
  for (int e = 0; e < 24; ++e){ s += v[e]; s2 += v[e]*v[e]; }
  s  += __shfl_xor(s, 1, 64);  s  += __shfl_xor(s, 2, 64);  s  += __shfl_xor(s, 4, 64);
  s2 += __shfl_xor(s2, 1, 64); s2 += __shfl_xor(s2, 2, 64); s2 += __shfl_xor(s2, 4, 64);
  if (sub == 0){
    float m = s*(1.f/192.f);
    float var = s2*(1.f/192.f) - m*m;
    st[r*2] = m; st[r*2+1] = rsqrtf(var + 1e-5f);
  }
}

// ---------------- workspace layout (bytes) ----------------
#define WS_KV   ((size_t)0)                     // 2*65536*384 bf16 = 100,663,296
#define WS_W1   ((size_t)100663296)             // qkv' : 36*6 tiles
#define WS_WKV  (WS_W1  + 221184)
#define WS_WQ   (WS_WKV + 147456)
#define WS_WP   (WS_WQ  + 73728)
#define WS_WM1  (WS_WP  + 73728)
#define WS_WM2  (WS_WM1 + 147456)
#define WS_WO   (WS_WM2 + 147456)
#define WS_C1   (WS_WO  + 73728)
#define WS_C2   (WS_C1  + 2304)
#define WS_C1O  (WS_C2  + 2304)
#define WS_C2O  (WS_C1O + 768)
#define WS_C1M  (WS_C2O + 768)
#define WS_C2M  (WS_C1M + 1536)
#define WS_NEED (WS_C2M + 1536)                 // = 101,557,248

// ---------------- prep: weight -> bf16 MFMA-fragment order (optionally * g[k]) ----------------
__global__ void k_swz(const float* __restrict__ src, const float* __restrict__ gv,
                      u16* __restrict__ dst, int KT, int K){
  int tile = blockIdx.x; int nt = tile / KT, kt = tile - nt*KT;
  int l = threadIdx.x;
  int row = nt*16 + (l & 15);
  int kb  = kt*32 + ((l>>4)<<3);
  const float* s = src + (size_t)row*K + kb;
  u16* d = dst + (size_t)tile*512 + l*8;
  #pragma unroll
  for (int e = 0; e < 8; ++e){
    float w = s[e];
    if (gv) w *= gv[kb + e];
    d[e] = f2bf(w);
  }
}
// c1[n] = sum_k W[n][k]*g[k]; c2[n] = sum_k W[n][k]*b[k]
__global__ void k_cvec(const float* __restrict__ W, const float* __restrict__ g,
                       const float* __restrict__ b, float* __restrict__ c1,
                       float* __restrict__ c2, int K){
  int n = blockIdx.x; int l = threadIdx.x;
  float s1 = 0.f, s2 = 0.f;
  for (int k = l; k < K; k += 64){
    float w = W[(size_t)n*K + k];
    s1 += w*g[k]; s2 += w*b[k];
  }
  #pragma unroll
  for (int d = 1; d < 64; d <<= 1){ s1 += __shfl_xor(s1, d, 64); s2 += __shfl_xor(s2, d, 64); }
  if (l == 0){ c1[n] = s1; c2[n] = s2; }
}

// ---------------- k_kv: per-pixel KV GEMM (dedup of unfold) ----------------
__global__ __launch_bounds__(512) void k_kv(const float* __restrict__ x,
                                            const u16* __restrict__ wkv,
                                            u16* __restrict__ KV){
  __shared__ __align__(16) u16 sA[64*LDW];
  const int blk = blockIdx.x;                // 2048
  const int batch = blk >> 10;
  const int pix0 = (blk & 1023) * 64;
  const float* xb = x + (size_t)batch*CH*65536;

  for (int idx = threadIdx.x; idx < 1536; idx += 512){
    int c = idx >> 3, s = idx & 7;
    const float* p = xb + (size_t)c*65536 + pix0 + s*8;
    float4 a = *reinterpret_cast<const float4*>(p);
    float4 b = *reinterpret_cast<const float4*>(p + 4);
    u16* d = &sA[(s*8)*LDW + c];
    d[0*LDW]=f2bf(a.x); d[1*LDW]=f2bf(a.y); d[2*LDW]=f2bf(a.z); d[3*LDW]=f2bf(a.w);
    d[4*LDW]=f2bf(b.x); d[5*LDW]=f2bf(b.y); d[6*LDW]=f2bf(b.z); d[7*LDW]=f2bf(b.w);
  }
  __syncthreads();

  const int w = threadIdx.x >> 6, l = threadIdx.x & 63;
  const int mt = w >> 1, half = w & 1;
  const f32x4 z4 = {0.f,0.f,0.f,0.f};
  f32x4 acc[12];
  #pragma unroll
  for (int j = 0; j < 12; ++j) acc[j] = z4;
  const int arow = mt*16 + (l & 15);
  for (int kt = 0; kt < 6; ++kt){
    bf16x8 a = afrag(sA, 0, LDW, arow, kt, l);
    #pragma unroll
    for (int j = 0; j < 12; ++j){
      int nt = half*12 + j;
      acc[j] = mfma16(a, bfrag(wkv, nt*6 + kt, l), acc[j]);
    }
  }
  u16* kvb = KV + ((size_t)batch*65536 + pix0)*384;
  const int rbase = mt*16 + ((l>>4)<<2);
  #pragma unroll
  for (int j = 0; j < 12; ++j){
    int col = (half*12 + j)*16 + (l & 15);
    #pragma unroll
    for (int r = 0; r < 4; ++r)
      kvb[(size_t)(rbase + r)*384 + col] = f2bf(acc[j][r]);
  }
}

// ---------------- k_msa: window MSA + MLP (MFMA); out = x + alpha * x_win ----------------
#define SX   0
#define SN   12800
#define SQKV 25600           // [64][576] bf16, XOR swizzled: u16col ^ ((row>>3&7)<<3)
#define SG   25600           // reuse: gelu [64][392]
#define SM   62464
#define SST  75264           // f32 stats[128]
#define POOLSZ 75520

__global__ __launch_bounds__(512) void k_msa(
    const float* __restrict__ x, const u16* __restrict__ ws16, const float* __restrict__ wsf,
    const float* __restrict__ rpe, const float* __restrict__ alpha_p, float* __restrict__ out)
{
  __shared__ __align__(16) u16 pool[POOLSZ];
  float* st = reinterpret_cast<float*>(pool + SST);
  const u16* W1  = ws16 + WS_W1/2;
  const u16* WP  = ws16 + WS_WP/2;
  const u16* WM1 = ws16 + WS_WM1/2;
  const u16* WM2 = ws16 + WS_WM2/2;
  const float* c1  = wsf + WS_C1/4;
  const float* c2  = wsf + WS_C2/4;
  const float* c1m = wsf + WS_C1M/4;
  const float* c2m = wsf + WS_C2M/4;

  const int tid = threadIdx.x;
  const int win = blockIdx.x;
  const int b  = win >> 10;
  const int wy = (win >> 5) & 31;
  const int wx = win & 31;
  const int hrow = wy*8, wcol = wx*8;
  const float* xb = x + (size_t)b*CH*HWD*HWD;
  float* outb = out + (size_t)b*CH*HWD*HWD;

  // P0: window -> sX bf16
  for (int j = tid; j < 1536; j += 512){
    int c = j >> 3, ty = j & 7;
    const float* src = xb + ((size_t)c*HWD + hrow + ty)*HWD + wcol;
    float4 a = *reinterpret_cast<const float4*>(src);
    float4 q = *reinterpret_cast<const float4*>(src + 4);
    u16* dst = &pool[SX + (ty*8)*LDW + c];
    dst[0*LDW]=f2bf(a.x); dst[1*LDW]=f2bf(a.y); dst[2*LDW]=f2bf(a.z); dst[3*LDW]=f2bf(a.w);
    dst[4*LDW]=f2bf(q.x); dst[5*LDW]=f2bf(q.y); dst[6*LDW]=f2bf(q.z); dst[7*LDW]=f2bf(q.w);
  }
  __syncthreads();
  ln_stats(pool + SX, st, tid);
  __syncthreads();

  const int w = tid >> 6, l = tid & 63;
  const int mt = w >> 1, half = w & 1;
  const int arow = mt*16 + (l & 15);
  const int rbase = mt*16 + ((l>>4)<<2);
  const f32x4 z4 = {0.f,0.f,0.f,0.f};

  // P2a: qkv = rs*(x @ W1'^T - m*c1) + c2  (LN folded), N=576
  {
    f32x4 acc[18];
    #pragma unroll
    for (int j = 0; j < 18; ++j) acc[j] = z4;
    for (int kt = 0; kt < 6; ++kt){
      bf16x8 a = afrag(pool, SX, LDW, arow, kt, l);
      #pragma unroll
      for (int j = 0; j < 18; ++j)
        acc[j] = mfma16(a, bfrag(W1, (half*18 + j)*6 + kt, l), acc[j]);
    }
    float mr[4], rr[4];
    #pragma unroll
    for (int r = 0; r < 4; ++r){ mr[r] = st[(rbase+r)*2]; rr[r] = st[(rbase+r)*2+1]; }
    #pragma unroll
    for (int j = 0; j < 18; ++j){
      int col = (half*18 + j)*16 + (l & 15);
      float c1v = c1[col], c2v = c2[col];
      #pragma unroll
      for (int r = 0; r < 4; ++r){
        int row = rbase + r;
        float v = rr[r]*(acc[j][r] - mr[r]*c1v) + c2v;
        pool[SQKV + row*576 + (col ^ (((row>>3)&7)<<3))] = f2bf(v);
      }
    }
  }
  __syncthreads();

  // P2b: attention, all heads, no inner syncs
  {
    const int t8 = tid >> 3, s8 = tid & 7;
    const int ry = t8 >> 3, rx = t8 & 7;
    const int swq = ((t8 >> 3) & 7) << 3;
    const int swk = s8 << 3;
    for (int h = 0; h < NH; ++h){
      float q24[24];
      #pragma unroll
      for (int seg = 0; seg < 3; ++seg){
        uint4 v = *reinterpret_cast<const uint4*>(pool + SQKV + t8*576 + ((h*24 + seg*8) ^ swq));
        up8(v, q24 + seg*8);
      }
      float p[8];
      #pragma unroll
      for (int j = 0; j < 8; ++j){
        int c = s8*8 + j;
        float k24[24];
        #pragma unroll
        for (int seg = 0; seg < 3; ++seg){
          uint4 v = *reinterpret_cast<const uint4*>(pool + SQKV + c*576 + ((192 + h*24 + seg*8) ^ swk));
          up8(v, k24 + seg*8);
        }
        float s = 0.f;
        #pragma unroll
        for (int e = 0; e < 24; ++e) s += q24[e]*k24[e];
        int cy = c >> 3, cx = c & 7;
        p[j] = s*SCALE + rpe[((ry-cy+7)*15 + (rx-cx+7))*NH + h];
      }
      float mx = p[0];
      #pragma unroll
      for (int j = 1; j < 8; ++j) mx = fmaxf(mx, p[j]);
      mx = fmaxf(mx, __shfl_xor(mx, 1, 64));
      mx = fmaxf(mx, __shfl_xor(mx, 2, 64));
      mx = fmaxf(mx, __shfl_xor(mx, 4, 64));
      float sum = 0.f;
      #pragma unroll
      for (int j = 0; j < 8; ++j){ p[j] = __expf(p[j] - mx); sum += p[j]; }
      sum += __shfl_xor(sum, 1, 64); sum += __shfl_xor(sum, 2, 64); sum += __shfl_xor(sum, 4, 64);
      float inv = 1.f / sum;
      float o24[24];
      #pragma unroll
      for (int e = 0; e < 24; ++e) o24[e] = 0.f;
      #pragma unroll
      for (int j = 0; j < 8; ++j){
        int c = s8*8 + j;
        float v24[24];
        #pragma unroll
        for (int seg = 0; seg < 3; ++seg){
          uint4 v = *reinterpret_cast<const uint4*>(pool + SQKV + c*576 + ((384 + h*24 + seg*8) ^ swk));
          up8(v, v24 + seg*8);
        }
        #pragma unroll
        for (int e = 0; e < 24; ++e) o24[e] += p[j]*v24[e];
      }
      #pragma unroll
      for (int e = 0; e < 24; ++e){
        o24[e] += __shfl_xor(o24[e], 1, 64);
        o24[e] += __shfl_xor(o24[e], 2, 64);
        o24[e] += __shfl_xor(o24[e], 4, 64);
      }
      u16* mrow = &pool[SM + t8*LDW + h*24 + s8*3];
      #pragma unroll
      for (int o = 0; o < 3; ++o) mrow[o] = f2bf(o24[s8*3 + o]*inv);
    }
  }
  __syncthreads();

  // P3: xw2 = msa @ wproj^T + x  -> sN
  {
    f32x4 acc[6];
    #pragma unroll
    for (int j = 0; j < 6; ++j) acc[j] = z4;
    for (int kt = 0; kt < 6; ++kt){
      bf16x8 a = afrag(pool, SM, LDW, arow, kt, l);
      #pragma unroll
      for (int j = 0; j < 6; ++j)
        acc[j] = mfma16(a, bfrag(WP, (half*6 + j)*6 + kt, l), acc[j]);
    }
    #pragma unroll
    for (int j = 0; j < 6; ++j){
      int col = (half*6 + j)*16 + (l & 15);
      #pragma unroll
      for (int r = 0; r < 4; ++r){
        int row = rbase + r;
        pool[SN + row*LDW + col] = f2bf(acc[j][r] + bf2f(pool[SX + row*LDW + col]));
      }
    }
  }
  __syncthreads();
  ln_stats(pool + SN, st, tid);   // LN2 stats
  __syncthreads();

  // P5: gelu(rs*(xw2 @ mlp1'^T - m*c1m) + c2m) -> sG [64][392]
  {
    f32x4 acc[12];
    #pragma unroll
    for (int j = 0; j < 12; ++j) acc[j] = z4;
    for (int kt = 0; kt < 6; ++kt){
      bf16x8 a = afrag(pool, SN, LDW, arow, kt, l);
      #pragma unroll
      for (int j = 0; j < 12; ++j)
        acc[j] = mfma16(a, bfrag(WM1, (half*12 + j)*6 + kt, l), acc[j]);
    }
    float mr[4], rr[4];
    #pragma unroll
    for (int r = 0; r < 4; ++r){ mr[r] = st[(rbase+r)*2]; rr[r] = st[(rbase+r)*2+1]; }
    #pragma unroll
    for (int j = 0; j < 12; ++j){
      int col = (half*12 + j)*16 + (l & 15);
      float c1v = c1m[col], c2v = c2m[col];
      #pragma unroll
      for (int r = 0; r < 4; ++r){
        float hv = rr[r]*(acc[j][r] - mr[r]*c1v) + c2v;
        float gl = 0.5f*hv*(1.f + erff(hv*0.70710678118654752f));
        pool[SG + (rbase + r)*392 + col] = f2bf(gl);
      }
    }
  }
  __syncthreads();

  // P6: x_win = gelu @ mlp2^T + xw2 -> sM
  {
    f32x4 acc[6];
    #pragma unroll
    for (int j = 0; j < 6; ++j) acc[j] = z4;
    for (int kt = 0; kt < 12; ++kt){
      bf16x8 a = afrag(pool, SG, 392, arow, kt, l);
      #pragma unroll
      for (int j = 0; j < 6; ++j)
        acc[j] = mfma16(a, bfrag(WM2, (half*6 + j)*12 + kt, l), acc[j]);
    }
    #pragma unroll
    for (int j = 0; j < 6; ++j){
      int col = (half*6 + j)*16 + (l & 15);
      #pragma unroll
      for (int r = 0; r < 4; ++r){
        int row = rbase + r;
        pool[SM + row*LDW + col] = f2bf(acc[j][r] + bf2f(pool[SN + row*LDW + col]));
      }
    }
  }
  __syncthreads();

  // P7: out = x + alpha * x_win
  float alpha = alpha_p[0];
  for (int j = tid; j < 1536; j += 512){
    int c = j >> 3, ty = j & 7;
    size_t goff = ((size_t)c*HWD + hrow + ty)*HWD + wcol;
    const float* src = xb + goff;
    float4 a = *reinterpret_cast<const float4*>(src);
    float4 q = *reinterpret_cast<const float4*>(src + 4);
    float wv[8];
    #pragma unroll
    for (int e = 0; e < 8; ++e) wv[e] = bf2f(pool[SM + (ty*8 + e)*LDW + c]);
    float4 o1 = make_float4(a.x + alpha*wv[0], a.y + alpha*wv[1], a.z + alpha*wv[2], a.w + alpha*wv[3]);
    float4 o2 = make_float4(q.x + alpha*wv[4], q.y + alpha*wv[5], q.z + alpha*wv[6], q.w + alpha*wv[7]);
    *reinterpret_cast<float4*>(outb + goff)     = o1;
    *reinterpret_cast<float4*>(outb + goff + 4) = o2;
  }
}

// ---------------- k_oca_attn: cross attention from precomputed KV; out += (1-alpha)*x_oca ----------------
#define OW   0
#define OQ   12800
#define OO   25600
#define OK_  38400
#define OV_  44160
#define OPIX 49920          // 144 ints (288 u16)
#define OST  50208          // f32 stats[128]
#define OPOOL 50464

__global__ __launch_bounds__(512) void k_oca_attn(
    const float* __restrict__ x, const u16* __restrict__ ws16, const float* __restrict__ wsf,
    const float* __restrict__ alpha_p, float* __restrict__ out)
{
  __shared__ __align__(16) u16 pool[OPOOL];
  float* st = reinterpret_cast<float*>(pool + OST);
  int* pixA = reinterpret_cast<int*>(pool + OPIX);
  const u16* KV = ws16 + WS_KV/2;
  const u16* WQ = ws16 + WS_WQ/2;
  const u16* WO = ws16 + WS_WO/2;
  const float* c1o = wsf + WS_C1O/4;
  const float* c2o = wsf + WS_C2O/4;

  const int tid = threadIdx.x;
  const int win = blockIdx.x;
  const int b  = win >> 10;
  const int wy = (win >> 5) & 31;
  const int wx = win & 31;
  const int hrow = wy*8, wcol = wx*8;
  const float* xb = x + (size_t)b*CH*HWD*HWD;
  float* outb = out + (size_t)b*CH*HWD*HWD;
  const size_t pixBase = (size_t)b*65536;

  // P0: window -> sW bf16; pixel map; stats
  for (int j = tid; j < 1536; j += 512){
    int c = j >> 3, ty = j & 7;
    const float* src = xb + ((size_t)c*HWD + hrow + ty)*HWD + wcol;
    float4 a = *reinterpret_cast<const float4*>(src);
    float4 q = *reinterpret_cast<const float4*>(src + 4);
    u16* dst = &pool[OW + (ty*8)*LDW + c];
    dst[0*LDW]=f2bf(a.x); dst[1*LDW]=f2bf(a.y); dst[2*LDW]=f2bf(a.z); dst[3*LDW]=f2bf(a.w);
    dst[4*LDW]=f2bf(q.x); dst[5*LDW]=f2bf(q.y); dst[6*LDW]=f2bf(q.z); dst[7*LDW]=f2bf(q.w);
  }
  if (tid < 144){
    int ti = tid / 12, tj = tid - ti*12;
    pixA[tid] = refl(hrow + ti - 2)*HWD + refl(wcol + tj - 2);
  }
  __syncthreads();
  ln_stats(pool + OW, st, tid);
  __syncthreads();

  const int w = tid >> 6, l = tid & 63;
  const int mt = w >> 1, half = w & 1;
  const int arow = mt*16 + (l & 15);
  const int rbase = mt*16 + ((l>>4)<<2);
  const f32x4 z4 = {0.f,0.f,0.f,0.f};

  // P1: q = rs*(x @ Wq'^T - m*c1o) + c2o -> sQ
  {
    f32x4 acc[6];
    #pragma unroll
    for (int j = 0; j < 6; ++j) acc[j] = z4;
    for (int kt = 0; kt < 6; ++kt){
      bf16x8 a = afrag(pool, OW, LDW, arow, kt, l);
      #pragma unroll
      for (int j = 0; j < 6; ++j)
        acc[j] = mfma16(a, bfrag(WQ, (half*6 + j)*6 + kt, l), acc[j]);
    }
    float mr[4], rr[4];
    #pragma unroll
    for (int r = 0; r < 4; ++r){ mr[r] = st[(rbase+r)*2]; rr[r] = st[(rbase+r)*2+1]; }
    #pragma unroll
    for (int j = 0; j < 6; ++j){
      int col = (half*6 + j)*16 + (l & 15);
      float c1v = c1o[col], c2v = c2o[col];
      #pragma unroll
      for (int r = 0; r < 4; ++r)
        pool[OQ + (rbase + r)*LDW + col] = f2bf(rr[r]*(acc[j][r] - mr[r]*c1v) + c2v);
    }
  }
  __syncthreads();

  const int t8 = tid >> 3, s8 = tid & 7;
  for (int h = 0; h < NH; ++h){
    // stage K_h, V_h (144 x 24 bf16 each) from KV workspace
    for (int i = tid; i < 432; i += 512){
      int tok = i / 3, seg = i - tok*3;
      const u16* src = KV + (pixBase + pixA[tok])*384 + h*24 + seg*8;
      *reinterpret_cast<uint4*>(pool + OK_ + tok*LDK + seg*8) = *reinterpret_cast<const uint4*>(src);
      *reinterpret_cast<uint4*>(pool + OV_ + tok*LDK + seg*8) = *reinterpret_cast<const uint4*>(src + 192);
    }
    __syncthreads();
    {
      float q24[24];
      #pragma unroll
      for (int seg = 0; seg < 3; ++seg){
        uint4 v = *reinterpret_cast<const uint4*>(pool + OQ + t8*LDW + h*24 + seg*8);
        up8(v, q24 + seg*8);
      }
      float p[18];
      #pragma unroll
      for (int j = 0; j < 18; ++j){
        int c = s8*18 + j;
        float k24[24];
        #pragma unroll
        for (int seg = 0; seg < 3; ++seg){
          uint4 v = *reinterpret_cast<const uint4*>(pool + OK_ + c*LDK + seg*8);
          up8(v, k24 + seg*8);
        }
        float s = 0.f;
        #pragma unroll
        for (int e = 0; e < 24; ++e) s += q24[e]*k24[e];
        p[j] = s*SCALE;
      }
      float mx = p[0];
      #pragma unroll
      for (int j = 1; j < 18; ++j) mx = fmaxf(mx, p[j]);
      mx = fmaxf(mx, __shfl_xor(mx, 1, 64));
      mx = fmaxf(mx, __shfl_xor(mx, 2, 64));
      mx = fmaxf(mx, __shfl_xor(mx, 4, 64));
      float sum = 0.f;
      #pragma unroll
      for (int j = 0; j < 18; ++j){ p[j] = __expf(p[j] - mx); sum += p[j]; }
      sum += __shfl_xor(sum, 1, 64); sum += __shfl_xor(sum, 2, 64); sum += __shfl_xor(sum, 4, 64);
      float inv = 1.f / sum;
      float o24[24];
      #pragma unroll
      for (int e = 0; e < 24; ++e) o24[e] = 0.f;
      #pragma unroll
      for (int j = 0; j < 18; ++j){
        int c = s8*18 + j;
        float v24[24];
        #pragma unroll
        for (int seg = 0; seg < 3; ++seg){
          uint4 v = *reinterpret_cast<const uint4*>(pool + OV_ + c*LDK + seg*8);
          up8(v, v24 + seg*8);
        }
        #pragma unroll
        for (int e = 0; e < 24; ++e) o24[e] += p[j]*v24[e];
      }
      #pragma unroll
      for (int e = 0; e < 24; ++e){
        o24[e] += __shfl_xor(o24[e], 1, 64);
        o24[e] += __shfl_xor(o24[e], 2, 64);
        o24[e] += __shfl_xor(o24[e], 4, 64);
      }
      u16* orow = &pool[OO + t8*LDW + h*24 + s8*3];
      #pragma unroll
      for (int o = 0; o < 3; ++o) orow[o] = f2bf(o24[s8*3 + o]*inv);
    }
    __syncthreads();
  }

  // P4: x_oca = attn @ oproj^T + x -> sQ (dead)
  {
    f32x4 acc[6];
    #pragma unroll
    for (int j = 0; j < 6; ++j) acc[j] = z4;
    for (int kt = 0; kt < 6; ++kt){
      bf16x8 a = afrag(pool, OO, LDW, arow, kt, l);
      #pragma unroll
      for (int j = 0; j < 6; ++j)
        acc[j] = mfma16(a, bfrag(WO, (half*6 + j)*6 + kt, l), acc[j]);
    }
    #pragma unroll
    for (int j = 0; j < 6; ++j){
      int col = (half*6 + j)*16 + (l & 15);
      #pragma unroll
      for (int r = 0; r < 4; ++r){
        int row = rbase + r;
        pool[OQ + row*LDW + col] = f2bf(acc[j][r] + bf2f(pool[OW + row*LDW + col]));
      }
    }
  }
  __syncthreads();

  // P5: out += (1-alpha) * x_oca
  float beta = 1.f - alpha_p[0];
  for (int j = tid; j < 1536; j += 512){
    int c = j >> 3, ty = j & 7;
    size_t goff = ((size_t)c*HWD + hrow + ty)*HWD + wcol;
    float* dst = outb + goff;
    float4 a = *reinterpret_cast<const float4*>(dst);
    float4 q = *reinterpret_cast<const float4*>(dst + 4);
    float wv[8];
    #pragma unroll
    for (int e = 0; e < 8; ++e) wv[e] = bf2f(pool[OQ + (ty*8 + e)*LDW + c]);
    float4 o1 = make_float4(a.x + beta*wv[0], a.y + beta*wv[1], a.z + beta*wv[2], a.w + beta*wv[3]);
    float4 o2 = make_float4(q.x + beta*wv[4], q.y + beta*wv[5], q.z + beta*wv[6], q.w + beta*wv[7]);
    *reinterpret_cast<float4*>(dst)     = o1;
    *reinterpret_cast<float4*>(dst + 4) = o2;
  }
}

// ================= FALLBACK (round-2, VALU-only, no workspace) =================
__device__ __forceinline__ void layernorm_fb(const u16* __restrict__ src, u16* __restrict__ dst,
                                             const float* __restrict__ g, const float* __restrict__ b,
                                             int tid)
{
  int r = tid >> 3, sub = tid & 7;
  const u16* row = src + r*LDW + sub*24;
  float v[24];
  float s = 0.f, s2 = 0.f;
  #pragma unroll
  for (int e = 0; e < 24; ++e){ v[e] = bf2f(row[e]); s += v[e]; s2 += v[e]*v[e]; }
  s  += __shfl_xor(s, 1, 64);  s  += __shfl_xor(s, 2, 64);  s  += __shfl_xor(s, 4, 64);
  s2 += __shfl_xor(s2, 1, 64); s2 += __shfl_xor(s2, 2, 64); s2 += __shfl_xor(s2, 4, 64);
  float m   = s * (1.f/192.f);
  float var = s2 * (1.f/192.f) - m*m;
  float rs  = rsqrtf(var + 1e-5f);
  u16* drow = dst + r*LDW + sub*24;
  #pragma unroll
  for (int e = 0; e < 24; ++e)
    drow[e] = f2bf((v[e] - m) * rs * g[sub*24+e] + b[sub*24+e]);
}
__device__ __forceinline__ void gemm83(const u16* __restrict__ a_lds,
                                       const float* __restrict__ w0,
                                       const float* __restrict__ w1,
                                       const float* __restrict__ w2,
                                       int tg, float (*acc)[3])
{
  for (int k0 = 0; k0 < 192; k0 += 8){
    float wv[3][8];
    ldw8(w0 + k0, wv[0]); ldw8(w1 + k0, wv[1]); ldw8(w2 + k0, wv[2]);
    #pragma unroll
    for (int tt = 0; tt < 8; ++tt){
      float a[8];
      up8(*reinterpret_cast<const uint4*>(a_lds + (tg*8+tt)*LDW + k0), a);
      #pragma unroll
      for (int e = 0; e < 8; ++e){
        acc[tt][0] += a[e]*wv[0][e];
        acc[tt][1] += a[e]*wv[1][e];
        acc[tt][2] += a[e]*wv[2][e];
      }
    }
  }
}
__global__ __launch_bounds__(512) void k_msa_fb(
    const float* __restrict__ x, const float* __restrict__ g1, const float* __restrict__ b1,
    const float* __restrict__ qkv_w, const float* __restrict__ rpe, const float* __restrict__ wproj,
    const float* __restrict__ g2, const float* __restrict__ b2,
    const float* __restrict__ mlp1, const float* __restrict__ mlp2,
    const float* __restrict__ alpha_p, float* __restrict__ out)
{
  __shared__ __align__(16) u16 sX[64*LDW];
  __shared__ __align__(16) u16 sN[64*LDW];
  __shared__ __align__(16) u16 sM[64*LDW];
  __shared__ __align__(16) float sQ[64*QSTR];
  __shared__ __align__(16) float sK[64*QSTR];
  __shared__ __align__(16) float sV[64*QSTR];
  const int tid = threadIdx.x;
  const int win = blockIdx.x;
  const int b  = win >> 10;
  const int wy = (win >> 5) & 31;
  const int wx = win & 31;
  const int hrow = wy*8, wcol = wx*8;
  const float* xb = x + (size_t)b*CH*HWD*HWD;
  float* outb = out + (size_t)b*CH*HWD*HWD;
  for (int j = tid; j < 1536; j += 512){
    int c = j >> 3, ty = j & 7;
    const float* src = xb + ((size_t)c*HWD + hrow + ty)*HWD + wcol;
    float4 a = *reinterpret_cast<const float4*>(src);
    float4 q = *reinterpret_cast<const float4*>(src + 4);
    u16* dst = &sX[(ty*8)*LDW + c];
    dst[0*LDW]=f2bf(a.x); dst[1*LDW]=f2bf(a.y); dst[2*LDW]=f2bf(a.z); dst[3*LDW]=f2bf(a.w);
    dst[4*LDW]=f2bf(q.x); dst[5*LDW]=f2bf(q.y); dst[6*LDW]=f2bf(q.z); dst[7*LDW]=f2bf(q.w);
  }
  __syncthreads();
  layernorm_fb(sX, sN, g1, b1, tid);
  __syncthreads();
  const int t8 = tid >> 3, s8 = tid & 7;
  for (int h = 0; h < NH; ++h){
    {
      const u16* arow = &sN[t8*LDW];
      float acc[9];
      #pragma unroll
      for (int o = 0; o < 9; ++o) acc[o] = 0.f;
      const float* wp[9];
      #pragma unroll
      for (int o = 0; o < 3; ++o){
        const float* base = qkv_w + (size_t)(h*24 + s8*3 + o)*192;
        wp[o] = base; wp[3+o] = base + 192*192; wp[6+o] = base + 2*192*192;
      }
      for (int k0 = 0; k0 < 192; k0 += 8){
        float a[8]; up8(*reinterpret_cast<const uint4*>(arow + k0), a);
        #pragma unroll
        for (int o = 0; o < 9; ++o){
          float wv[8]; ldw8(wp[o] + k0, wv);
          #pragma unroll
          for (int e = 0; e < 8; ++e) acc[o] += a[e]*wv[e];
        }
      }
      #pragma unroll
      for (int o = 0; o < 3; ++o){
        sQ[t8*QSTR + s8*3 + o] = acc[o];
        sK[t8*QSTR + s8*3 + o] = acc[3+o];
        sV[t8*QSTR + s8*3 + o] = acc[6+o];
      }
    }
    __syncthreads();
    {
      float q24[24];
      #pragma unroll
      for (int e = 0; e < 24; ++e) q24[e] = sQ[t8*QSTR + e];
      const int ry = t8 >> 3, rx = t8 & 7;
      float p[8];
      #pragma unroll
      for (int j = 0; j < 8; ++j){
        int c = s8*8 + j;
        const float* kr = &sK[c*QSTR];
        float s = 0.f;
        #pragma unroll
        for (int e = 0; e < 24; ++e) s += q24[e]*kr[e];
        int cy = c >> 3, cx = c & 7;
        p[j] = s*SCALE + rpe[((ry-cy+7)*15 + (rx-cx+7))*NH + h];
      }
      float mx = p[0];
      #pragma unroll
      for (int j = 1; j < 8; ++j) mx = fmaxf(mx, p[j]);
      mx = fmaxf(mx, __shfl_xor(mx, 1, 64));
      mx = fmaxf(mx, __shfl_xor(mx, 2, 64));
      mx = fmaxf(mx, __shfl_xor(mx, 4, 64));
      float sum = 0.f;
      #pragma unroll
      for (int j = 0; j < 8; ++j){ p[j] = __expf(p[j] - mx); sum += p[j]; }
      sum += __shfl_xor(sum, 1, 64); sum += __shfl_xor(sum, 2, 64); sum += __shfl_xor(sum, 4, 64);
      float inv = 1.f / sum;
      float o24[24];
      #pragma unroll
      for (int e = 0; e < 24; ++e) o24[e] = 0.f;
      #pragma unroll
      for (int j = 0; j < 8; ++j){
        const float* vr = &sV[(s8*8 + j)*QSTR];
        #pragma unroll
        for (int e = 0; e < 24; ++e) o24[e] += p[j]*vr[e];
      }
      #pragma unroll
      for (int e = 0; e < 24; ++e){
        o24[e] += __shfl_xor(o24[e], 1, 64);
        o24[e] += __shfl_xor(o24[e], 2, 64);
        o24[e] += __shfl_xor(o24[e], 4, 64);
      }
      u16* mrow = &sM[t8*LDW + h*24 + s8*3];
      #pragma unroll
      for (int o = 0; o < 3; ++o) mrow[o] = f2bf(o24[s8*3 + o]*inv);
    }
    __syncthreads();
  }
  const int tg = tid >> 6, cg = tid & 63;
  {
    float acc[8][3];
    #pragma unroll
    for (int tt = 0; tt < 8; ++tt){ acc[tt][0]=0.f; acc[tt][1]=0.f; acc[tt][2]=0.f; }
    gemm83(sM, wproj + (size_t)(cg*3+0)*192, wproj + (size_t)(cg*3+1)*192, wproj + (size_t)(cg*3+2)*192, tg, acc);
    #pragma unroll
    for (int tt = 0; tt < 8; ++tt)
      #pragma unroll
      for (int j = 0; j < 3; ++j){
        int t = tg*8+tt, c = cg*3+j;
        sN[t*LDW + c] = f2bf(acc[tt][j] + bf2f(sX[t*LDW + c]));
      }
  }
  __syncthreads();
  layernorm_fb(sN, sX, g2, b2, tid);
  __syncthreads();
  float facc[8][3];
  #pragma unroll
  for (int tt = 0; tt < 8; ++tt){ facc[tt][0]=0.f; facc[tt][1]=0.f; facc[tt][2]=0.f; }
  for (int half = 0; half < 2; ++half){
    {
      float acc[8][3];
      #pragma unroll
      for (int tt = 0; tt < 8; ++tt){ acc[tt][0]=0.f; acc[tt][1]=0.f; acc[tt][2]=0.f; }
      gemm83(sX, mlp1 + (size_t)(half*192 + cg*3+0)*192, mlp1 + (size_t)(half*192 + cg*3+1)*192,
                 mlp1 + (size_t)(half*192 + cg*3+2)*192, tg, acc);
      #pragma unroll
      for (int tt = 0; tt < 8; ++tt)
        #pragma unroll
        for (int j = 0; j < 3; ++j){
          float vv = acc[tt][j];
          sM[(tg*8+tt)*LDW + cg*3+j] = f2bf(0.5f*vv*(1.f + erff(vv*0.70710678118654752f)));
        }
    }
    __syncthreads();
    gemm83(sM, mlp2 + (size_t)(cg*3+0)*384 + half*192, mlp2 + (size_t)(cg*3+1)*384 + half*192,
               mlp2 + (size_t)(cg*3+2)*384 + half*192, tg, facc);
    __syncthreads();
  }
  #pragma unroll
  for (int tt = 0; tt < 8; ++tt)
    #pragma unroll
    for (int j = 0; j < 3; ++j){
      int t = tg*8+tt, c = cg*3+j;
      sM[t*LDW + c] = f2bf(bf2f(sN[t*LDW + c]) + facc[tt][j]);
    }
  __syncthreads();
  float alpha = alpha_p[0];
  for (int j = tid; j < 1536; j += 512){
    int c = j >> 3, ty = j & 7;
    size_t goff = ((size_t)c*HWD + hrow + ty)*HWD + wcol;
    const float* src = xb + goff;
    float4 a = *reinterpret_cast<const float4*>(src);
    float4 q = *reinterpret_cast<const float4*>(src + 4);
    float wv[8];
    #pragma unroll
    for (int e = 0; e < 8; ++e) wv[e] = bf2f(sM[(ty*8 + e)*LDW + c]);
    float4 o1 = make_float4(a.x + alpha*wv[0], a.y + alpha*wv[1], a.z + alpha*wv[2], a.w + alpha*wv[3]);
    float4 o2 = make_float4(q.x + alpha*wv[4], q.y + alpha*wv[5], q.z + alpha*wv[6], q.w + alpha*wv[7]);
    *reinterpret_cast<float4*>(outb + goff)     = o1;
    *reinterpret_cast<float4*>(outb + goff + 4) = o2;
  }
}
__global__ __launch_bounds__(512) void k_oca_fb(
    const float* __restrict__ x, const float* __restrict__ og_p, const float* __restrict__ ob_p,
    const float* __restrict__ q_w, const float* __restrict__ kv_w, const float* __restrict__ oproj,
    const float* __restrict__ alpha_p, float* __restrict__ out)
{
  __shared__ __align__(16) u16 sW[64*LDW];
  __shared__ __align__(16) u16 sN[64*LDW];
  __shared__ __align__(16) u16 sQa[64*LDW];
  __shared__ __align__(16) u16 sU[144*LDW];
  __shared__ __align__(16) u16 sKb[144*32];
  __shared__ __align__(16) u16 sVb[144*32];
  const int tid = threadIdx.x;
  const int win = blockIdx.x;
  const int b  = win >> 10;
  const int wy = (win >> 5) & 31;
  const int wx = win & 31;
  const int hrow = wy*8, wcol = wx*8;
  const float* xb = x + (size_t)b*CH*HWD*HWD;
  float* outb = out + (size_t)b*CH*HWD*HWD;
  for (int j = tid; j < 1536; j += 512){
    int c = j >> 3, ty = j & 7;
    const float* src = xb + ((size_t)c*HWD + hrow + ty)*HWD + wcol;
    float4 a = *reinterpret_cast<const float4*>(src);
    float4 q = *reinterpret_cast<const float4*>(src + 4);
    u16* dst = &sW[(ty*8)*LDW + c];
    dst[0*LDW]=f2bf(a.x); dst[1*LDW]=f2bf(a.y); dst[2*LDW]=f2bf(a.z); dst[3*LDW]=f2bf(a.w);
    dst[4*LDW]=f2bf(q.x); dst[5*LDW]=f2bf(q.y); dst[6*LDW]=f2bf(q.z); dst[7*LDW]=f2bf(q.w);
  }
  for (int i = tid; i < 144*192; i += 512){
    int c = i / 144, t = i - c*144;
    int ti = t / 12, tj = t - ti*12;
    sU[t*LDW + c] = f2bf(xb[((size_t)c*HWD + refl(hrow + ti - 2))*HWD + refl(wcol + tj - 2)]);
  }
  __syncthreads();
  layernorm_fb(sW, sN, og_p, ob_p, tid);
  __syncthreads();
  const int tg = tid >> 6, cg = tid & 63;
  {
    float acc[8][3];
    #pragma unroll
    for (int tt = 0; tt < 8; ++tt){ acc[tt][0]=0.f; acc[tt][1]=0.f; acc[tt][2]=0.f; }
    gemm83(sN, q_w + (size_t)(cg*3+0)*192, q_w + (size_t)(cg*3+1)*192, q_w + (size_t)(cg*3+2)*192, tg, acc);
    #pragma unroll
    for (int tt = 0; tt < 8; ++tt)
      #pragma unroll
      for (int j = 0; j < 3; ++j)
        sQa[(tg*8+tt)*LDW + cg*3+j] = f2bf(acc[tt][j]);
  }
  __syncthreads();
  const int t8 = tid >> 3, s8 = tid & 7;
  for (int h = 0; h < NH; ++h){
    for (int i = tid; i < 144*24; i += 512){
      int tok = i / 24, d = i - tok*24;
      const float* kw = kv_w + (size_t)(h*24 + d)*192;
      const float* vw = kv_w + (size_t)(192 + h*24 + d)*192;
      const u16* arow = &sU[tok*LDW];
      float ka[4] = {0.f,0.f,0.f,0.f}, va[4] = {0.f,0.f,0.f,0.f};
      for (int k0 = 0; k0 < 192; k0 += 8){
        float a[8]; up8(*reinterpret_cast<const uint4*>(arow + k0), a);
        float kk[8]; ldw8(kw + k0, kk);
        float vv[8]; ldw8(vw + k0, vv);
        #pragma unroll
        for (int e = 0; e < 8; ++e){ ka[e&3] += a[e]*kk[e]; va[e&3] += a[e]*vv[e]; }
      }
      sKb[tok*32 + d] = f2bf(ka[0]+ka[1]+ka[2]+ka[3]);
      sVb[tok*32 + d] = f2bf(va[0]+va[1]+va[2]+va[3]);
    }
    __syncthreads();
    {
      float q24[24];
      #pragma unroll
      for (int e = 0; e < 24; ++e) q24[e] = bf2f(sQa[t8*LDW + h*24 + e]);
      float p[18];
      #pragma unroll
      for (int j = 0; j < 18; ++j){
        int c = s8*18 + j;
        const u16* kr = &sKb[c*32];
        float s = 0.f;
        #pragma unroll
        for (int e = 0; e < 24; ++e) s += q24[e]*bf2f(kr[e]);
        p[j] = s*SCALE;
      }
      float mx = p[0];
      #pragma unroll
      for (int j = 1; j < 18; ++j) mx = fmaxf(mx, p[j]);
      mx = fmaxf(mx, __shfl_xor(mx, 1, 64));
      mx = fmaxf(mx, __shfl_xor(mx, 2, 64));
      mx = fmaxf(mx, __shfl_xor(mx, 4, 64));
      float sum = 0.f;
      #pragma unroll
      for (int j = 0; j < 18; ++j){ p[j] = __expf(p[j] - mx); sum += p[j]; }
      sum += __shfl_xor(sum, 1, 64); sum += __shfl_xor(sum, 2, 64); sum += __shfl_xor(sum, 4, 64);
      float inv = 1.f / sum;
      float o24[24];
      #pragma unroll
      for (int e = 0; e < 24; ++e) o24[e] = 0.f;
      #pragma unroll
      for (int j = 0; j < 18; ++j){
        const u16* vr = &sVb[(s8*18 + j)*32];
        #pragma unroll
        for (int e = 0; e < 24; ++e) o24[e] += p[j]*bf2f(vr[e]);
      }
      #pragma unroll
      for (int e = 0; e < 24; ++e){
        o24[e] += __shfl_xor(o24[e], 1, 64);
        o24[e] += __shfl_xor(o24[e], 2, 64);
        o24[e] += __shfl_xor(o24[e], 4, 64);
      }
      u16* orow = &sN[t8*LDW + h*24 + s8*3];
      #pragma unroll
      for (int o = 0; o < 3; ++o) orow[o] = f2bf(o24[s8*3 + o]*inv);
    }
    __syncthreads();
  }
  {
    float acc[8][3];
    #pragma unroll
    for (int tt = 0; tt < 8; ++tt){ acc[tt][0]=0.f; acc[tt][1]=0.f; acc[tt][2]=0.f; }
    gemm83(sN, oproj + (size_t)(cg*3+0)*192, oproj + (size_t)(cg*3+1)*192, oproj + (size_t)(cg*3+2)*192, tg, acc);
    #pragma unroll
    for (int tt = 0; tt < 8; ++tt)
      #pragma unroll
      for (int j = 0; j < 3; ++j){
        int t = tg*8+tt, c = cg*3+j;
        sQa[t*LDW + c] = f2bf(acc[tt][j] + bf2f(sW[t*LDW + c]));
      }
  }
  __syncthreads();
  float beta = 1.f - alpha_p[0];
  for (int j = tid; j < 1536; j += 512){
    int c = j >> 3, ty = j & 7;
    size_t goff = ((size_t)c*HWD + hrow + ty)*HWD + wcol;
    float* dst = outb + goff;
    float4 a = *reinterpret_cast<const float4*>(dst);
    float4 q = *reinterpret_cast<const float4*>(dst + 4);
    float wv[8];
    #pragma unroll
    for (int e = 0; e < 8; ++e) wv[e] = bf2f(sQa[(ty*8 + e)*LDW + c]);
    float4 o1 = make_float4(a.x + beta*wv[0], a.y + beta*wv[1], a.z + beta*wv[2], a.w + beta*wv[3]);
    float4 o2 = make_float4(q.x + beta*wv[4], q.y + beta*wv[5], q.z + beta*wv[6], q.w + beta*wv[7]);
    *reinterpret_cast<float4*>(dst)     = o1;
    *reinterpret_cast<float4*>(dst + 4) = o2;
  }
}

extern "C" void kernel_launch(void* const* d_in, const int* in_sizes, int n_in,
                              void* d_out, int out_size, void* d_ws, size_t ws_size,
                              hipStream_t stream) {
  const float* x     = (const float*)d_in[0];
  const float* g1    = (const float*)d_in[1];
  const float* b1    = (const float*)d_in[2];
  const float* qkvw  = (const float*)d_in[3];
  const float* rpe   = (const float*)d_in[4];
  const float* wproj = (const float*)d_in[5];
  const float* g2    = (const float*)d_in[6];
  const float* b2    = (const float*)d_in[7];
  const float* mlp1  = (const float*)d_in[8];
  const float* mlp2  = (const float*)d_in[9];
  const float* alpha = (const float*)d_in[10];
  const float* og    = (const float*)d_in[11];
  const float* ob    = (const float*)d_in[12];
  const float* q_w   = (const float*)d_in[13];
  const float* kv_w  = (const float*)d_in[14];
  const float* oproj = (const float*)d_in[15];
  float* out = (float*)d_out;

  if (ws_size >= (size_t)WS_NEED) {
    u16*   ws16 = (u16*)d_ws;
    float* wsf  = (float*)d_ws;
    // weight prep: fragment-order bf16 (+ LN-gamma folds)
    k_swz<<<36*6, 64, 0, stream>>>(qkvw,  g1,      ws16 + WS_W1/2,  6, 192);
    k_swz<<<24*6, 64, 0, stream>>>(kv_w,  nullptr, ws16 + WS_WKV/2, 6, 192);
    k_swz<<<12*6, 64, 0, stream>>>(q_w,   og,      ws16 + WS_WQ/2,  6, 192);
    k_swz<<<12*6, 64, 0, stream>>>(wproj, nullptr, ws16 + WS_WP/2,  6, 192);
    k_swz<<<24*6, 64, 0, stream>>>(mlp1,  g2,      ws16 + WS_WM1/2, 6, 192);
    k_swz<<<12*12,64, 0, stream>>>(mlp2,  nullptr, ws16 + WS_WM2/2, 12, 384);
    k_swz<<<12*6, 64, 0, stream>>>(oproj, nullptr, ws16 + WS_WO/2,  6, 192);
    k_cvec<<<576, 64, 0, stream>>>(qkvw, g1, b1, (float*)((char*)d_ws + WS_C1),  (float*)((char*)d_ws + WS_C2),  192);
    k_cvec<<<192, 64, 0, stream>>>(q_w,  og, ob, (float*)((char*)d_ws + WS_C1O), (float*)((char*)d_ws + WS_C2O), 192);
    k_cvec<<<384, 64, 0, stream>>>(mlp1, g2, b2, (float*)((char*)d_ws + WS_C1M), (float*)((char*)d_ws + WS_C2M), 192);
    // per-pixel KV (dedup of overlapping-window unfold)
    k_kv<<<2048, 512, 0, stream>>>(x, ws16 + WS_WKV/2, ws16 + WS_KV/2);
    // fused branches
    k_msa<<<2048, 512, 0, stream>>>(x, ws16, wsf, rpe, alpha, out);
    k_oca_attn<<<2048, 512, 0, stream>>>(x, ws16, wsf, alpha, out);
  } else {
    k_msa_fb<<<2048, 512, 0, stream>>>(x, g1, b1, qkvw, rpe, wproj, g2, b2, mlp1, mlp2, alpha, out);
    k_oca_fb<<<2048, 512, 0, stream>>>(x, og, ob, q_w, kv_w, oproj, alpha, out);
  }
}